// Round 1
// baseline (828.127 us; speedup 1.0000x reference)
//
#include <hip/hip_runtime.h>
#include <hip/hip_bf16.h>

// Problem constants
#define DD 1024
#define NTOK 4096
#define KK 16
// M = NTOK*KK = 65536

typedef __attribute__((ext_vector_type(4))) float f32x4;
typedef __attribute__((ext_vector_type(8))) short bf16x8;

__device__ __forceinline__ ushort f2bf(float f) {
  unsigned b = __builtin_bit_cast(unsigned, f);
  b += 0x7FFFu + ((b >> 16) & 1u);   // RNE
  return (ushort)(b >> 16);
}

// LDS XOR swizzle: flip byte bits 4,5 keyed on bits 7,8 ((row>>1)&3 for 64B rows).
// Involution; preserves 16B chunks; gives <=2-way bank conflicts for the
// stride-64B fragment-read pattern (lane reads row=l&15, colb=(l>>4)*16).
__device__ __forceinline__ unsigned swz(unsigned a) {
  return a ^ (((a >> 7) & 3u) << 4);
}

__device__ __forceinline__ bf16x8 cvt8(const float* p) {
  f32x4 a = *(const f32x4*)p;
  f32x4 b = *(const f32x4*)(p + 4);
  bf16x8 r;
  r[0] = (short)f2bf(a[0]); r[1] = (short)f2bf(a[1]);
  r[2] = (short)f2bf(a[2]); r[3] = (short)f2bf(a[3]);
  r[4] = (short)f2bf(b[0]); r[5] = (short)f2bf(b[1]);
  r[6] = (short)f2bf(b[2]); r[7] = (short)f2bf(b[3]);
  return r;
}

// ---------------------------------------------------------------------------
// prep: pack weights as bf16 B^T tiles [kt][n (1024)][kk (32)] so b-fragments
// are contiguous 16B per lane. Bmain: W_logic rows 1024..3071 (routed|delta).
// Bk1: W_logic rows 0..1023. Bgate: Wg[0:1024] ; Wg[1024+i]+Wg[2048+i].
// ---------------------------------------------------------------------------
__global__ __launch_bounds__(256) void prep_kernel(
    const float* __restrict__ Wl, const float* __restrict__ Wg,
    ushort* __restrict__ Bmain, ushort* __restrict__ Bk1,
    ushort* __restrict__ Bgate) {
  const int SZM = 2048 * 1024;          // Bmain elements
  const int SZ1 = 1024 * 1024;          // Bk1
  const int SZG = 2048 * 1024;          // Bgate
  const int total = SZM + SZ1 + SZG;
  for (int d = blockIdx.x * blockDim.x + threadIdx.x; d < total;
       d += gridDim.x * blockDim.x) {
    if (d < SZM) {
      int kt = d >> 15, nn = (d >> 5) & 1023, kk = d & 31;
      int e = kt * 32 + kk;                         // 0..2047
      Bmain[d] = f2bf(Wl[(size_t)(1024 + e) * 1024 + nn]);
    } else if (d < SZM + SZ1) {
      int x = d - SZM;
      int kt = x >> 15, nn = (x >> 5) & 1023, kk = x & 31;
      Bk1[x] = f2bf(Wl[(size_t)(kt * 32 + kk) * 1024 + nn]);
    } else {
      int x = d - SZM - SZ1;
      int kt = x >> 15, nn = (x >> 5) & 1023, kk = x & 31;
      int e = kt * 32 + kk;                         // 0..2047
      float v = Wg[(size_t)e * 1024 + nn];
      if (e >= 1024) v += Wg[(size_t)(e + 1024) * 1024 + nn];
      Bgate[x] = f2bf(v);
    }
  }
}

// ---------------------------------------------------------------------------
// gemm_small: C = act(A_f32 @ Bpack + bias). 128x128 tile, 4 waves (2x2),
// wave tile 64x64 via 16x16x32 bf16 MFMA. A read as f32 + cvt in regs,
// B frags direct from L2 (packed layout). ACT: 0=none, 1=sigmoid.
// kt < NSPLIT reads A0, else A1 (k offset rebased).
// grid: (M/128, 1024/128)
// ---------------------------------------------------------------------------
template <int NKT, int NSPLIT, int ACT>
__global__ __launch_bounds__(256, 3) void gemm_small(
    const float* __restrict__ A0, const float* __restrict__ A1,
    const ushort* __restrict__ Bp, const float* __restrict__ bias,
    float* __restrict__ Cout) {
  int tid = threadIdx.x, l = tid & 63, wid = tid >> 6;
  int wm = wid & 1, wn = wid >> 1;
  int mbase = blockIdx.x * 128 + wm * 64;
  int nbase = blockIdx.y * 128 + wn * 64;
  int lr = l & 15, lh = l >> 4;
  f32x4 acc[4][4] = {};
#pragma unroll 1
  for (int kt = 0; kt < NKT; ++kt) {
    const float* As = (kt < NSPLIT) ? A0 : A1;
    int ke = ((kt < NSPLIT) ? kt : kt - NSPLIT) * 32 + lh * 8;
    bf16x8 af[4];
#pragma unroll
    for (int mf = 0; mf < 4; ++mf)
      af[mf] = cvt8(As + (size_t)(mbase + mf * 16 + lr) * 1024 + ke);
    bf16x8 bf[4];
#pragma unroll
    for (int nf = 0; nf < 4; ++nf)
      bf[nf] = *(const bf16x8*)(Bp + (size_t)kt * 32768 +
                                (size_t)(nbase + nf * 16 + lr) * 32 + lh * 8);
#pragma unroll
    for (int nf = 0; nf < 4; ++nf)
#pragma unroll
      for (int mf = 0; mf < 4; ++mf)
        acc[mf][nf] = __builtin_amdgcn_mfma_f32_16x16x32_bf16(
            af[mf], bf[nf], acc[mf][nf], 0, 0, 0);
  }
#pragma unroll
  for (int nf = 0; nf < 4; ++nf) {
    int col = nbase + nf * 16 + lr;
    float bs = bias[col];
#pragma unroll
    for (int mf = 0; mf < 4; ++mf)
#pragma unroll
      for (int j = 0; j < 4; ++j) {
        int row = mbase + mf * 16 + lh * 4 + j;
        float v = acc[mf][nf][j] + bs;
        if (ACT == 1) v = 1.0f / (1.0f + expf(-v));
        Cout[(size_t)row * 1024 + col] = v;
      }
  }
}

// ---------------------------------------------------------------------------
// main fused kernel: per block 64 M-rows (= 4 tokens x 16 k) x full 1024 cols.
// 8 waves (1x8), wave tile 64x128. K-dim 2048 (routed then delta), 64 steps.
// A: f32->bf16 cvt, LDS double-buffered, XOR-swizzled. B: direct L2 frags.
// Epilogue: +t_part, exact GELU, LayerNorm (cross-wave LDS reduce), inline
// softmax(sim_row), weighted K-reduce -> arg_summary.
// ---------------------------------------------------------------------------
__global__ __launch_bounds__(512, 2) void main_kernel(
    const float* __restrict__ routed, const float* __restrict__ delta,
    const float* __restrict__ simrow, const ushort* __restrict__ Bmain,
    const float* __restrict__ tpart, const float* __restrict__ gamma,
    const float* __restrict__ beta, float* __restrict__ out_arg) {
  __shared__ ushort Ab[2][2048];        // two 4KB A tiles [64][32] bf16 (swz)
  __shared__ float ldsG[1024], ldsB2[1024];
  __shared__ float ldsW[64];            // softmax weights for 4 tokens x 16 k
  __shared__ float lnS[64 * 8], lnQ[64 * 8];

  int tid = threadIdx.x, l = tid & 63, wid = tid >> 6;
  int bx = blockIdx.x;                  // tokens bx*4 .. bx*4+3
  int lr = l & 15, lh = l >> 4;

  for (int i = tid; i < 1024; i += 512) { ldsG[i] = gamma[i]; ldsB2[i] = beta[i]; }
  if (tid < 4) {                        // softmax over K=16 for token bx*4+tid
    int n = bx * 4 + tid;
    float sv[16], mx = -1e30f;
#pragma unroll
    for (int j = 0; j < 16; ++j) { sv[j] = simrow[n * 16 + j]; mx = fmaxf(mx, sv[j]); }
    float s = 0.f;
#pragma unroll
    for (int j = 0; j < 16; ++j) { sv[j] = expf(sv[j] - mx); s += sv[j]; }
    float inv = 1.0f / s;
#pragma unroll
    for (int j = 0; j < 16; ++j) ldsW[tid * 16 + j] = sv[j] * inv;
  }

  // A staging geometry: thread handles logical bytes a = tid*8 of the 4KB tile
  const int arow = tid >> 3;                 // 0..63
  const int akoff = (tid & 7) * 4;           // f32 element offset in 32-k tile
  const size_t am = (size_t)(bx * 64 + arow) * 1024 + akoff;
  const unsigned adst = swz((unsigned)tid * 8);

  {  // stage kt=0 (routed)
    f32x4 v = *(const f32x4*)(routed + am);
    uint2 w;
    w.x = (unsigned)f2bf(v[0]) | ((unsigned)f2bf(v[1]) << 16);
    w.y = (unsigned)f2bf(v[2]) | ((unsigned)f2bf(v[3]) << 16);
    *(uint2*)((char*)Ab[0] + adst) = w;
  }
  __syncthreads();

  f32x4 acc[4][8] = {};
#pragma unroll 1
  for (int kt = 0; kt < 64; ++kt) {
    int cur = kt & 1;
    // B fragments for this step, direct from L2 (coalesced 1KB/wave/load)
    bf16x8 bf[8];
#pragma unroll
    for (int nf = 0; nf < 8; ++nf)
      bf[nf] = *(const bf16x8*)(Bmain + (size_t)kt * 32768 +
                                (size_t)(wid * 128 + nf * 16 + lr) * 32 + lh * 8);
    // A fragments from LDS (swizzled)
    bf16x8 af[4];
#pragma unroll
    for (int mf = 0; mf < 4; ++mf) {
      unsigned a = (unsigned)(mf * 16 + lr) * 64 + (unsigned)lh * 16;
      af[mf] = *(const bf16x8*)((const char*)Ab[cur] + swz(a));
    }
    // issue next A-tile global load early (hidden under MFMA)
    bool have = (kt + 1) < 64;
    f32x4 av;
    if (have) {
      int kt2 = kt + 1;
      const float* asrc = (kt2 < 32) ? routed : delta;
      av = *(const f32x4*)(asrc + am + (size_t)(kt2 & 31) * 32);
    }
#pragma unroll
    for (int nf = 0; nf < 8; ++nf)
#pragma unroll
      for (int mf = 0; mf < 4; ++mf)
        acc[mf][nf] = __builtin_amdgcn_mfma_f32_16x16x32_bf16(
            af[mf], bf[nf], acc[mf][nf], 0, 0, 0);
    if (have) {
      uint2 w;
      w.x = (unsigned)f2bf(av[0]) | ((unsigned)f2bf(av[1]) << 16);
      w.y = (unsigned)f2bf(av[2]) | ((unsigned)f2bf(av[3]) << 16);
      *(uint2*)((char*)Ab[cur ^ 1] + adst) = w;
    }
    __syncthreads();
  }

  // ---- fused epilogue ----
  // acc[mf][nf][j]: local row mf*16 + lh*4 + j (= token mf, k = lh*4+j),
  //                 col wid*128 + nf*16 + lr
  const float inv_d = 1.0f / 1024.0f;
  float gam[8], bet[8];
#pragma unroll
  for (int nf = 0; nf < 8; ++nf) {
    int c = wid * 128 + nf * 16 + lr;
    gam[nf] = ldsG[c]; bet[nf] = ldsB2[c];
  }
#pragma unroll
  for (int mf = 0; mf < 4; ++mf) {
    int tokrow = bx * 4 + mf;
    float s[4] = {0, 0, 0, 0}, q[4] = {0, 0, 0, 0};
#pragma unroll
    for (int nf = 0; nf < 8; ++nf) {
      float tp = tpart[(size_t)tokrow * 1024 + wid * 128 + nf * 16 + lr];
#pragma unroll
      for (int j = 0; j < 4; ++j) {
        float h = acc[mf][nf][j] + tp;
        float g = 0.5f * h * (1.0f + erff(h * 0.70710678118654752f));
        acc[mf][nf][j] = g;
        s[j] += g; q[j] += g * g;
      }
    }
#pragma unroll
    for (int j = 0; j < 4; ++j) {
#pragma unroll
      for (int d = 1; d <= 8; d <<= 1) {
        s[j] += __shfl_xor(s[j], d, 64);
        q[j] += __shfl_xor(q[j], d, 64);
      }
    }
    if (lr == 0) {
#pragma unroll
      for (int j = 0; j < 4; ++j) {
        int row = mf * 16 + lh * 4 + j;
        lnS[row * 8 + wid] = s[j];
        lnQ[row * 8 + wid] = q[j];
      }
    }
  }
  __syncthreads();
#pragma unroll
  for (int mf = 0; mf < 4; ++mf) {
    float mu[4], rs[4], wk[4];
#pragma unroll
    for (int j = 0; j < 4; ++j) {
      int row = mf * 16 + lh * 4 + j;
      float S = 0.f, Q = 0.f;
#pragma unroll
      for (int w = 0; w < 8; ++w) { S += lnS[row * 8 + w]; Q += lnQ[row * 8 + w]; }
      float m_ = S * inv_d;
      mu[j] = m_;
      rs[j] = rsqrtf(Q * inv_d - m_ * m_ + 1e-5f);
      wk[j] = ldsW[row];
    }
#pragma unroll
    for (int nf = 0; nf < 8; ++nf) {
      float ws = 0.f;
#pragma unroll
      for (int j = 0; j < 4; ++j) {
        float y = (acc[mf][nf][j] - mu[j]) * rs[j] * gam[nf] + bet[nf];
        ws += wk[j] * y;
      }
      ws += __shfl_xor(ws, 16, 64);
      ws += __shfl_xor(ws, 32, 64);
      if (lh == 0)
        out_arg[(size_t)(bx * 4 + mf) * 1024 + wid * 128 + nf * 16 + lr] = ws;
    }
  }
}

// ---------------------------------------------------------------------------
extern "C" void kernel_launch(void* const* d_in, const int* in_sizes, int n_in,
                              void* d_out, int out_size, void* d_ws, size_t ws_size,
                              hipStream_t stream) {
  const float* token  = (const float*)d_in[0];   // [4096,1024]
  const float* routed = (const float*)d_in[1];   // [4096,16,1024]
  const float* simrow = (const float*)d_in[2];   // [4096,16]
  const float* delta  = (const float*)d_in[3];   // [4096,16,1024]
  const float* Wl     = (const float*)d_in[4];   // [3072,1024]
  const float* bl     = (const float*)d_in[5];   // [1024]
  const float* gamma  = (const float*)d_in[6];
  const float* beta   = (const float*)d_in[7];
  const float* Wg     = (const float*)d_in[8];   // [3072,1024]
  const float* bg     = (const float*)d_in[9];

  // workspace layout (26 MB)
  char* ws = (char*)d_ws;
  ushort* Bmain = (ushort*)(ws);                         // 4 MB
  ushort* Bk1   = (ushort*)(ws + (4u << 20));            // 2 MB
  ushort* Bgate = (ushort*)(ws + (6u << 20));            // 4 MB
  float*  tpart = (float*)(ws + (10u << 20));            // 16 MB

  float* out_arg  = (float*)d_out;                       // [4096,1024]
  float* out_gate = out_arg + (size_t)4096 * 1024;       // [4096,1024]

  prep_kernel<<<1024, 256, 0, stream>>>(Wl, Wg, Bmain, Bk1, Bgate);
  // t_part = token @ W1 + b_logic
  gemm_small<32, 32, 0><<<dim3(32, 8), 256, 0, stream>>>(
      token, token, Bk1, bl, tpart);
  // fused main: rd-GEMM + gelu + LN + weighted sum -> arg_summary
  main_kernel<<<1024, 512, 0, stream>>>(
      routed, delta, simrow, Bmain, tpart, gamma, beta, out_arg);
  // gate = sigmoid(token @ Wg1 + arg @ (Wg2+Wg3) + b_gate)
  gemm_small<64, 32, 1><<<dim3(32, 8), 256, 0, stream>>>(
      token, out_arg, Bgate, bg, out_gate);
}

// Round 4
// 632.017 us; speedup vs baseline: 1.3103x; 1.3103x over previous
//
#include <hip/hip_runtime.h>
#include <hip/hip_bf16.h>

// Problem constants: D=1024, N=4096, K=16, M = N*K = 65536, K-dim main = 2048

typedef __attribute__((ext_vector_type(4))) float f32x4;
typedef __attribute__((ext_vector_type(8))) short bf16x8;

__device__ __forceinline__ ushort f2bf(float f) {
  unsigned b = __builtin_bit_cast(unsigned, f);
  b += 0x7FFFu + ((b >> 16) & 1u);   // RNE
  return (ushort)(b >> 16);
}
__device__ __forceinline__ unsigned pk2(float a, float b) {
  return (unsigned)f2bf(a) | ((unsigned)f2bf(b) << 16);
}

// LDS XOR swizzle for the A tile (verified in passing R1 kernel)
__device__ __forceinline__ unsigned swz(unsigned a) {
  return a ^ (((a >> 7) & 3u) << 4);
}

__device__ __forceinline__ bf16x8 cvt8(const float* p) {
  f32x4 a = *(const f32x4*)p;
  f32x4 b = *(const f32x4*)(p + 4);
  bf16x8 r;
  r[0] = (short)f2bf(a[0]); r[1] = (short)f2bf(a[1]);
  r[2] = (short)f2bf(a[2]); r[3] = (short)f2bf(a[3]);
  r[4] = (short)f2bf(b[0]); r[5] = (short)f2bf(b[1]);
  r[6] = (short)f2bf(b[2]); r[7] = (short)f2bf(b[3]);
  return r;
}

// ---------------------------------------------------------------------------
// prep: LDS tile-transpose weight packer (coalesced reads AND writes).
// mode 0 (bid<512):  Bmain packed layout: flat = kt*32768 + wg*4096 + c*8 + m,
//                    chunk c = nf*64 + lane; value = Wl[1024+kt*32+(lane>>4)*8+m]
//                                                      [wg*128+nf*16+(lane&15)]
// mode 1 (512..768): Bk1 layout [kt][nn][q*8+m] from Wl rows 0..1023
// mode 2 (768..1280): Bgate same layout from Wg rows kt*32 (+ row+1024 summed
//                    when kt>=32)
// ---------------------------------------------------------------------------
__global__ __launch_bounds__(256) void prep_kernel(
    const float* __restrict__ Wl, const float* __restrict__ Wg,
    ushort* __restrict__ Bmain, ushort* __restrict__ Bk1,
    ushort* __restrict__ Bgate) {
  __shared__ float L[32][129];
  int t = threadIdx.x;
  int bid = blockIdx.x;
  const float* src; int row0, mode, kt, wg; ushort* dst;
  if (bid < 512)      { mode = 0; kt = bid >> 3;        wg = bid & 7; src = Wl; row0 = 1024 + kt * 32; dst = Bmain; }
  else if (bid < 768) { mode = 1; kt = (bid - 512) >> 3; wg = (bid - 512) & 7; src = Wl; row0 = kt * 32; dst = Bk1; }
  else                { mode = 2; kt = (bid - 768) >> 3; wg = (bid - 768) & 7; src = Wg; row0 = kt * 32; dst = Bgate; }
  int col0 = wg * 128;
  bool dosum = (mode == 2) && (kt >= 32);
#pragma unroll
  for (int p = 0; p < 4; ++p) {
    int r = p * 8 + (t >> 5), c = (t & 31) * 4;
    const float* sp = src + (size_t)(row0 + r) * 1024 + col0 + c;
    f32x4 v = *(const f32x4*)sp;
    if (dosum) { f32x4 v2 = *(const f32x4*)(sp + (size_t)1024 * 1024); v += v2; }
    L[r][c] = v[0]; L[r][c + 1] = v[1]; L[r][c + 2] = v[2]; L[r][c + 3] = v[3];
  }
  __syncthreads();
  if (mode == 0) {
    for (int c = t; c < 512; c += 256) {
      int nf = c >> 6, lane = c & 63, lr_ = lane & 15, lh_ = lane >> 4;
      bf16x8 o;
#pragma unroll
      for (int m = 0; m < 8; ++m) o[m] = (short)f2bf(L[lh_ * 8 + m][nf * 16 + lr_]);
      *(bf16x8*)(dst + (size_t)kt * 32768 + wg * 4096 + c * 8) = o;
    }
  } else {
    for (int c = t; c < 512; c += 256) {
      int nn = c >> 2, q = c & 3;
      bf16x8 o;
#pragma unroll
      for (int m = 0; m < 8; ++m) o[m] = (short)f2bf(L[q * 8 + m][nn]);
      *(bf16x8*)(dst + (size_t)kt * 32768 + (size_t)(wg * 128 + nn) * 32 + q * 8) = o;
    }
  }
}

// ---------------------------------------------------------------------------
// gemm_small: C = act(A_f32 @ Bpack + bias). 64x128 tile, 4 waves (2x2),
// wave tile 32x64. grid (M/64, 8) = 512 blocks -> 2 blocks/CU.
// ---------------------------------------------------------------------------
template <int NKT, int NSPLIT, int ACT>
__global__ __launch_bounds__(256) void gemm_small(
    const float* __restrict__ A0, const float* __restrict__ A1,
    const ushort* __restrict__ Bp, const float* __restrict__ bias,
    float* __restrict__ Cout) {
  int tid = threadIdx.x, l = tid & 63, wid = tid >> 6;
  int wm = wid & 1, wn = wid >> 1;
  int mbase = blockIdx.x * 64 + wm * 32;
  int nbase = blockIdx.y * 128 + wn * 64;
  int lr = l & 15, lh = l >> 4;
  f32x4 acc[2][4] = {};
#pragma unroll 1
  for (int kt = 0; kt < NKT; ++kt) {
    const float* As = (kt < NSPLIT) ? A0 : A1;
    int ke = ((kt < NSPLIT) ? kt : kt - NSPLIT) * 32 + lh * 8;
    bf16x8 af[2];
#pragma unroll
    for (int mf = 0; mf < 2; ++mf)
      af[mf] = cvt8(As + (size_t)(mbase + mf * 16 + lr) * 1024 + ke);
    bf16x8 bf[4];
#pragma unroll
    for (int nf = 0; nf < 4; ++nf)
      bf[nf] = *(const bf16x8*)(Bp + (size_t)kt * 32768 +
                                (size_t)(nbase + nf * 16 + lr) * 32 + lh * 8);
#pragma unroll
    for (int nf = 0; nf < 4; ++nf)
#pragma unroll
      for (int mf = 0; mf < 2; ++mf)
        acc[mf][nf] = __builtin_amdgcn_mfma_f32_16x16x32_bf16(
            af[mf], bf[nf], acc[mf][nf], 0, 0, 0);
  }
#pragma unroll
  for (int nf = 0; nf < 4; ++nf) {
    int col = nbase + nf * 16 + lr;
    float bs = bias[col];
#pragma unroll
    for (int mf = 0; mf < 2; ++mf)
#pragma unroll
      for (int j = 0; j < 4; ++j) {
        int row = mbase + mf * 16 + lh * 4 + j;
        float v = acc[mf][nf][j] + bs;
        if (ACT == 1) v = 1.0f / (1.0f + expf(-v));
        Cout[(size_t)row * 1024 + col] = v;
      }
  }
}

// ---------------------------------------------------------------------------
// main fused kernel — R1-verified structure (static __shared__, __syncthreads,
// B global->reg) with the NEW packed Bmain layout (fully-coalesced B reads:
// consecutive lanes read consecutive 16B chunks -> 1KB/wave/instruction).
// Per block: 64 M-rows (= 4 tokens x 16 k) x 1024 cols, 8 waves (1x8).
// A: f32 global -> reg -> cvt bf16 -> swizzled LDS, double-buffered.
// Epilogue: +t_part, exact GELU, LayerNorm (cross-wave LDS reduce), inline
// softmax(sim_row), weighted K-reduce -> arg_summary.
// ---------------------------------------------------------------------------
__global__ __launch_bounds__(512, 2) void main_kernel(
    const float* __restrict__ routed, const float* __restrict__ delta,
    const float* __restrict__ simrow, const ushort* __restrict__ Bmain,
    const float* __restrict__ tpart, const float* __restrict__ gamma,
    const float* __restrict__ beta, float* __restrict__ out_arg) {
  __shared__ ushort Ab[2][2048];        // two 4KB A tiles [64][32] bf16 (swz)
  __shared__ float ldsG[1024], ldsB2[1024];
  __shared__ float ldsW[64];            // softmax weights for 4 tokens x 16 k
  __shared__ float lnS[64 * 8], lnQ[64 * 8];

  int tid = threadIdx.x, l = tid & 63, wid = tid >> 6;
  int bx = blockIdx.x;                  // tokens bx*4 .. bx*4+3
  int lr = l & 15, lh = l >> 4;

  for (int i = tid; i < 1024; i += 512) { ldsG[i] = gamma[i]; ldsB2[i] = beta[i]; }
  if (tid < 4) {                        // softmax over K=16 for token bx*4+tid
    int n = bx * 4 + tid;
    float sv[16], mx = -1e30f;
#pragma unroll
    for (int j = 0; j < 16; ++j) { sv[j] = simrow[n * 16 + j]; mx = fmaxf(mx, sv[j]); }
    float s = 0.f;
#pragma unroll
    for (int j = 0; j < 16; ++j) { sv[j] = expf(sv[j] - mx); s += sv[j]; }
    float inv = 1.0f / s;
#pragma unroll
    for (int j = 0; j < 16; ++j) ldsW[tid * 16 + j] = sv[j] * inv;
  }

  // A staging geometry: thread handles logical bytes a = tid*8 of the 4KB tile
  const int arow = tid >> 3;                 // 0..63
  const int akoff = (tid & 7) * 4;           // f32 element offset in 32-k tile
  const size_t am = (size_t)(bx * 64 + arow) * 1024 + akoff;
  const unsigned adst = swz((unsigned)tid * 8);

  {  // stage kt=0 (routed)
    f32x4 v = *(const f32x4*)(routed + am);
    uint2 w;
    w.x = pk2(v[0], v[1]);
    w.y = pk2(v[2], v[3]);
    *(uint2*)((char*)Ab[0] + adst) = w;
  }
  __syncthreads();

  f32x4 acc[4][8] = {};
#pragma unroll 1
  for (int kt = 0; kt < 64; ++kt) {
    int cur = kt & 1;
    // B fragments, NEW packed layout: lane l reads chunk nf*64+l -> coalesced
    bf16x8 bf[8];
#pragma unroll
    for (int nf = 0; nf < 8; ++nf)
      bf[nf] = *(const bf16x8*)(Bmain + (size_t)kt * 32768 +
                                (size_t)wid * 4096 + (size_t)nf * 512 + l * 8);
    // A fragments from LDS (swizzled)
    bf16x8 af[4];
#pragma unroll
    for (int mf = 0; mf < 4; ++mf) {
      unsigned a = (unsigned)(mf * 16 + lr) * 64 + (unsigned)lh * 16;
      af[mf] = *(const bf16x8*)((const char*)Ab[cur] + swz(a));
    }
    // issue next A-tile global load early (hidden under MFMA)
    bool have = (kt + 1) < 64;
    f32x4 av;
    if (have) {
      int kt2 = kt + 1;
      const float* asrc = (kt2 < 32) ? routed : delta;
      av = *(const f32x4*)(asrc + am + (size_t)(kt2 & 31) * 32);
    }
#pragma unroll
    for (int nf = 0; nf < 8; ++nf)
#pragma unroll
      for (int mf = 0; mf < 4; ++mf)
        acc[mf][nf] = __builtin_amdgcn_mfma_f32_16x16x32_bf16(
            af[mf], bf[nf], acc[mf][nf], 0, 0, 0);
    if (have) {
      uint2 w;
      w.x = pk2(av[0], av[1]);
      w.y = pk2(av[2], av[3]);
      *(uint2*)((char*)Ab[cur ^ 1] + adst) = w;
    }
    __syncthreads();
  }

  // ---- fused epilogue ----
  // acc[mf][nf][j]: local row mf*16 + lh*4 + j (= token mf, k = lh*4+j),
  //                 col wid*128 + nf*16 + lr
  const float inv_d = 1.0f / 1024.0f;
  float gam[8], bet[8];
#pragma unroll
  for (int nf = 0; nf < 8; ++nf) {
    int c = wid * 128 + nf * 16 + lr;
    gam[nf] = ldsG[c]; bet[nf] = ldsB2[c];
  }
#pragma unroll
  for (int mf = 0; mf < 4; ++mf) {
    int tokrow = bx * 4 + mf;
    float s[4] = {0, 0, 0, 0}, q[4] = {0, 0, 0, 0};
#pragma unroll
    for (int nf = 0; nf < 8; ++nf) {
      float tp = tpart[(size_t)tokrow * 1024 + wid * 128 + nf * 16 + lr];
#pragma unroll
      for (int j = 0; j < 4; ++j) {
        float h = acc[mf][nf][j] + tp;
        float g = 0.5f * h * (1.0f + erff(h * 0.70710678118654752f));
        acc[mf][nf][j] = g;
        s[j] += g; q[j] += g * g;
      }
    }
#pragma unroll
    for (int j = 0; j < 4; ++j) {
#pragma unroll
      for (int d = 1; d <= 8; d <<= 1) {
        s[j] += __shfl_xor(s[j], d, 64);
        q[j] += __shfl_xor(q[j], d, 64);
      }
    }
    if (lr == 0) {
#pragma unroll
      for (int j = 0; j < 4; ++j) {
        int row = mf * 16 + lh * 4 + j;
        lnS[row * 8 + wid] = s[j];
        lnQ[row * 8 + wid] = q[j];
      }
    }
  }
  __syncthreads();
#pragma unroll
  for (int mf = 0; mf < 4; ++mf) {
    float mu[4], rs[4], wk[4];
#pragma unroll
    for (int j = 0; j < 4; ++j) {
      int row = mf * 16 + lh * 4 + j;
      float S = 0.f, Q = 0.f;
#pragma unroll
      for (int w = 0; w < 8; ++w) { S += lnS[row * 8 + w]; Q += lnQ[row * 8 + w]; }
      float m_ = S * inv_d;
      mu[j] = m_;
      rs[j] = rsqrtf(Q * inv_d - m_ * m_ + 1e-5f);
      wk[j] = ldsW[row];
    }
#pragma unroll
    for (int nf = 0; nf < 8; ++nf) {
      float ws = 0.f;
#pragma unroll
      for (int j = 0; j < 4; ++j) {
        float y = (acc[mf][nf][j] - mu[j]) * rs[j] * gam[nf] + bet[nf];
        ws += wk[j] * y;
      }
      ws += __shfl_xor(ws, 16, 64);
      ws += __shfl_xor(ws, 32, 64);
      if (lh == 0)
        out_arg[(size_t)(bx * 4 + mf) * 1024 + wid * 128 + nf * 16 + lr] = ws;
    }
  }
}

// ---------------------------------------------------------------------------
extern "C" void kernel_launch(void* const* d_in, const int* in_sizes, int n_in,
                              void* d_out, int out_size, void* d_ws, size_t ws_size,
                              hipStream_t stream) {
  const float* token  = (const float*)d_in[0];
  const float* routed = (const float*)d_in[1];
  const float* simrow = (const float*)d_in[2];
  const float* delta  = (const float*)d_in[3];
  const float* Wl     = (const float*)d_in[4];
  const float* bl     = (const float*)d_in[5];
  const float* gamma  = (const float*)d_in[6];
  const float* beta   = (const float*)d_in[7];
  const float* Wg     = (const float*)d_in[8];
  const float* bg     = (const float*)d_in[9];

  char* ws = (char*)d_ws;
  ushort* Bmain = (ushort*)(ws);                         // 4 MB
  ushort* Bk1   = (ushort*)(ws + (4u << 20));            // 2 MB
  ushort* Bgate = (ushort*)(ws + (6u << 20));            // 4 MB
  float*  tpart = (float*)(ws + (10u << 20));            // 16 MB

  float* out_arg  = (float*)d_out;
  float* out_gate = out_arg + (size_t)4096 * 1024;

  prep_kernel<<<1280, 256, 0, stream>>>(Wl, Wg, Bmain, Bk1, Bgate);
  gemm_small<32, 32, 0><<<dim3(64, 8), 256, 0, stream>>>(
      token, token, Bk1, bl, tpart);
  main_kernel<<<1024, 512, 0, stream>>>(
      routed, delta, simrow, Bmain, tpart, gamma, beta, out_arg);
  gemm_small<64, 32, 1><<<dim3(64, 8), 256, 0, stream>>>(
      token, out_arg, Bgate, bg, out_gate);
}